// Round 1
// baseline (180.928 us; speedup 1.0000x reference)
//
#include <hip/hip_runtime.h>

#define S 4
#define B 64
#define D 32
#define N 784
#define P 2
#define L 10
#define HALF 392
#define NSTEP 391  // HALF - 1

// Broadcast lane `lane`'s value of v to all lanes (compiles to v_readlane -> SGPR).
__device__ __forceinline__ float bcast(float v, int lane) {
    return __uint_as_float(__builtin_amdgcn_readlane(__float_as_uint(v), lane));
}

// One wave per (side, s, b) chain. Lane = (p, j): p = lane>>5, j = lane&31.
// Each step: t_p[j] = sum_i v[i] * A[i][p][j]  (v broadcast via readlane),
// then v_new[j] = x0*t_0[j] + x1*t_1[j] via one shfl_xor(32) half-swap.
__global__ __launch_bounds__(64) void chain_kernel(
    const float* __restrict__ x,        // (B, N, P)
    const float* __restrict__ A_first,  // (S, D, P)
    const float* __restrict__ A_left,   // (S, 391, D, P, D)
    const float* __restrict__ A_right,  // (S, 391, D, P, D)
    const float* __restrict__ A_last,   // (S, D, P)
    float* __restrict__ ws_v)           // [side][s][b][D]
{
    const int blk  = blockIdx.x;   // 512 blocks
    const int pair = blk & 7;      // side*4 + s  -> same (side,s) shares an XCD
    const int b    = blk >> 3;     // 0..63
    const int side = pair >> 2;
    const int s    = pair & 3;
    const int lane = threadIdx.x;  // 0..63
    const int p    = lane >> 5;
    const int j    = lane & 31;

    const float* xb = x + b * (N * P);
    float v;

    if (side == 0) {
        // v0 from A_first and x[b,0]
        const float a0 = A_first[s * D * P + j * P + 0];
        const float a1 = A_first[s * D * P + j * P + 1];
        v = fmaf(a0, xb[0], a1 * xb[1]);
        const float* Abase = A_left + (size_t)s * (NSTEP * D * P * D);
        for (int n = 1; n <= NSTEP; ++n) {
            // column (p, j) of slice n-1: stride P*D floats between i's; coalesced across lanes
            const float* M = Abase + (n - 1) * (D * P * D) + p * D + j;
            const float x0 = xb[n * P + 0];
            const float x1 = xb[n * P + 1];
            float t0 = 0.f, t1 = 0.f;
            #pragma unroll
            for (int i = 0; i < D; i += 2) {
                t0 = fmaf(bcast(v, i),     M[i * (P * D)],       t0);
                t1 = fmaf(bcast(v, i + 1), M[(i + 1) * (P * D)], t1);
            }
            const float t     = t0 + t1;
            const float other = __shfl_xor(t, 32);
            v = (p == 0) ? fmaf(x0, t, x1 * other) : fmaf(x1, t, x0 * other);
        }
    } else {
        // r0 from A_last and x[b, N-1]
        const float a0 = A_last[s * D * P + j * P + 0];
        const float a1 = A_last[s * D * P + j * P + 1];
        v = fmaf(a0, xb[(N - 1) * P + 0], a1 * xb[(N - 1) * P + 1]);
        const float* Abase = A_right + (size_t)s * (NSTEP * D * P * D);
        for (int m = NSTEP - 1; m >= 0; --m) {
            // row (i=j, p) of slice m: contiguous 32 floats -> float4 loads (128B aligned)
            const float4* R4 = reinterpret_cast<const float4*>(
                Abase + m * (D * P * D) + j * (P * D) + p * D);
            const float x0 = xb[(HALF + m) * P + 0];
            const float x1 = xb[(HALF + m) * P + 1];
            float t0 = 0.f, t1 = 0.f;
            #pragma unroll
            for (int q = 0; q < 8; ++q) {
                const float4 rv = R4[q];
                t0 = fmaf(rv.x, bcast(v, 4 * q + 0), t0);
                t1 = fmaf(rv.y, bcast(v, 4 * q + 1), t1);
                t0 = fmaf(rv.z, bcast(v, 4 * q + 2), t0);
                t1 = fmaf(rv.w, bcast(v, 4 * q + 3), t1);
            }
            const float t     = t0 + t1;
            const float other = __shfl_xor(t, 32);
            v = (p == 0) ? fmaf(x0, t, x1 * other) : fmaf(x1, t, x0 * other);
        }
    }
    if (p == 0)
        ws_v[(side * S + s) * (B * D) + b * D + j] = v;
}

// Per (s,b): out_l = sum_j (sum_d v[d] * A_label[s][d][l][j]) * r[j]
__global__ __launch_bounds__(64) void label_kernel(
    const float* __restrict__ ws_v,     // [side][s][b][D]
    const float* __restrict__ A_label,  // (S, D, L, D)
    float* __restrict__ ws_o)           // [b][l][s]
{
    const int blk  = blockIdx.x;  // S*B = 256
    const int s    = blk & 3;
    const int b    = blk >> 2;
    const int lane = threadIdx.x;
    const int h    = lane >> 5;   // label half: h=0 -> l=0..4, h=1 -> l=5..9
    const int j    = lane & 31;

    const float vj = ws_v[(0 * S + s) * (B * D) + b * D + j];
    const float rj = ws_v[(1 * S + s) * (B * D) + b * D + j];

    #pragma unroll
    for (int q = 0; q < 5; ++q) {
        const int l = h * 5 + q;
        float w = 0.f;
        #pragma unroll
        for (int d = 0; d < D; ++d)
            w = fmaf(bcast(vj, d), A_label[((s * D + d) * L + l) * D + j], w);
        float c = w * rj;
        c += __shfl_xor(c, 1);
        c += __shfl_xor(c, 2);
        c += __shfl_xor(c, 4);
        c += __shfl_xor(c, 8);
        c += __shfl_xor(c, 16);
        if (j == 0) ws_o[(b * L + l) * S + s] = c;
    }
}

__global__ void prod_kernel(const float* __restrict__ ws_o, float* __restrict__ out) {
    const int t = blockIdx.x * blockDim.x + threadIdx.x;
    if (t < B * L) {
        const float* o = ws_o + t * S;
        out[t] = o[0] * o[1] * o[2] * o[3];
    }
}

extern "C" void kernel_launch(void* const* d_in, const int* in_sizes, int n_in,
                              void* d_out, int out_size, void* d_ws, size_t ws_size,
                              hipStream_t stream) {
    const float* x       = (const float*)d_in[0];
    const float* A_first = (const float*)d_in[1];
    const float* A_left  = (const float*)d_in[2];
    const float* A_label = (const float*)d_in[3];
    const float* A_right = (const float*)d_in[4];
    const float* A_last  = (const float*)d_in[5];
    float* out  = (float*)d_out;
    float* ws_v = (float*)d_ws;               // 2*S*B*D = 16384 floats
    float* ws_o = ws_v + 2 * S * B * D;       // B*L*S  =  2560 floats

    chain_kernel<<<dim3(2 * S * B), dim3(64), 0, stream>>>(
        x, A_first, A_left, A_right, A_last, ws_v);
    label_kernel<<<dim3(S * B), dim3(64), 0, stream>>>(ws_v, A_label, ws_o);
    prod_kernel<<<dim3((B * L + 255) / 256), dim3(256), 0, stream>>>(ws_o, out);
}